// Round 1
// baseline (274.922 us; speedup 1.0000x reference)
//
#include <hip/hip_runtime.h>
#include <math.h>

#define HW 9216
#define WD 96
#define NC 128

typedef unsigned short u16;
typedef __attribute__((ext_vector_type(8))) short short8;
typedef __attribute__((ext_vector_type(4))) float v4f;

__device__ __forceinline__ int rfl(int v){ return __builtin_amdgcn_readfirstlane(v); }
__device__ __forceinline__ float bu2f(u16 s){ return __uint_as_float(((unsigned)s)<<16); }
__device__ __forceinline__ u16 f2b(float f){ unsigned u = __float_as_uint(f);
  return (u16)((u + 0x7fffu + ((u>>16)&1u))>>16); }

// ---------------- K0: weight prep ----------------
__global__ __launch_bounds__(256) void prep_weights(const float* __restrict__ pw_w,
    const float* __restrict__ off_w, const float* __restrict__ dc_w,
    u16* __restrict__ wpwb, u16* __restrict__ wob, u16* __restrict__ wdcb){
  int t = blockIdx.x*256 + threadIdx.x;
  if (t < 16384) wpwb[t] = f2b(pw_w[t]);
  if (t < 36864){ int o = t/1152, r = t - o*1152; int k = r>>7, c = r&127;
                  wob[t] = (o<18) ? f2b(off_w[(o*128+c)*9+k]) : (u16)0; }
  if (t < 147456){ int o = t/1152, r = t - o*1152; int k = r>>7, c = r&127;
                   wdcb[t] = f2b(dc_w[(o*128+c)*9 + k]); }
}

// ---------------- K1: depthwise 3x3 + bias (NCHW fp32) ----------------
__global__ __launch_bounds__(256) void dw_conv(const float* __restrict__ x,
    const float* __restrict__ w, const float* __restrict__ bias, float* __restrict__ h1){
  int n = blockIdx.x*256 + threadIdx.x;
  int bc = rfl(n / HW);
  int p = n - bc*HW;
  int c = bc & 127;
  int yy = p / WD, xx = p - (p/WD)*WD;
  const float* xc = x + (size_t)bc*HW;
  float acc = bias[c];
  #pragma unroll
  for (int r=0;r<3;r++){
    int y2 = yy + r - 1;
    #pragma unroll
    for (int cc2=0;cc2<3;cc2++){
      int x2 = xx + cc2 - 1;
      if (y2>=0 && y2<96 && x2>=0 && x2<96)
        acc = fmaf(w[c*9 + r*3 + cc2], xc[y2*WD + x2], acc);
    }
  }
  h1[n] = acc;
}

// ---------------- K2: pointwise 1x1 via MFMA ----------------
__global__ __launch_bounds__(256) void pw_mfma(const float* __restrict__ h1,
    const u16* __restrict__ wpwb, const float* __restrict__ pw_b, float* __restrict__ h2){
  __shared__ short Aw[128*136];
  __shared__ short Bw[128*68];
  int blk = blockIdx.x; int row0 = blk*64;
  int b = rfl(row0/HW); int pbase = rfl(row0 - b*HW);
  int t = threadIdx.x;
  #pragma unroll
  for (int i=0;i<8;i++){
    int idx = i*256 + t; int o = idx>>4, seg = idx&15;
    *(short8*)&Aw[o*136 + seg*8] = *(const short8*)(wpwb + o*128 + seg*8);
  }
  #pragma unroll
  for (int i=0;i<8;i++){
    int idx = i*256 + t; int c = idx>>4, seg = idx&15;
    float4 v = *(const float4*)(h1 + (size_t)(b*NC+c)*HW + pbase + seg*4);
    ushort4 pk = make_ushort4(f2b(v.x), f2b(v.y), f2b(v.z), f2b(v.w));
    *(ushort4*)&Bw[c*68 + seg*4] = pk;
  }
  __syncthreads();
  int w = rfl(t>>6); int l = t&63; int q = l>>4; int ln = l&15;
  v4f acc[8];
  #pragma unroll
  for (int mt=0;mt<8;mt++) acc[mt] = (v4f){0.f,0.f,0.f,0.f};
  #pragma unroll
  for (int ks=0;ks<4;ks++){
    short8 bf;
    #pragma unroll
    for (int j=0;j<8;j++) bf[j] = Bw[(ks*32 + q*8 + j)*68 + w*16 + ln];
    #pragma unroll
    for (int mt=0;mt<8;mt++){
      short8 af = *(short8*)&Aw[(mt*16+ln)*136 + ks*32 + q*8];
      acc[mt] = __builtin_amdgcn_mfma_f32_16x16x32_bf16(af, bf, acc[mt], 0,0,0);
    }
  }
  int px = pbase + w*16 + ln;
  #pragma unroll
  for (int mt=0;mt<8;mt++){
    #pragma unroll
    for (int r=0;r<4;r++){
      int o = mt*16 + q*4 + r;
      h2[(size_t)(b*NC+o)*HW + px] = acc[mt][r] + pw_b[o];
    }
  }
}

// ---------------- K3: InstanceNorm stats ----------------
__global__ __launch_bounds__(256) void inorm_stats(const float* __restrict__ h2, float* __restrict__ st){
  int bc = blockIdx.x;
  const float* src = h2 + (size_t)bc*HW;
  float s=0.f, ss=0.f;
  for (int i=threadIdx.x; i<HW; i+=256){ float v=src[i]; s+=v; ss=fmaf(v,v,ss); }
  #pragma unroll
  for (int off=32; off; off>>=1){ s += __shfl_down(s,off); ss += __shfl_down(ss,off); }
  __shared__ float rsm[2][4];
  int wave = threadIdx.x>>6, lane = threadIdx.x&63;
  if (lane==0){ rsm[0][wave]=s; rsm[1][wave]=ss; }
  __syncthreads();
  if (threadIdx.x==0){
    float S = rsm[0][0]+rsm[0][1]+rsm[0][2]+rsm[0][3];
    float SS= rsm[1][0]+rsm[1][1]+rsm[1][2]+rsm[1][3];
    float mu = S * (1.f/9216.f);
    float var = SS * (1.f/9216.f) - mu*mu;
    st[bc*2]   = mu;
    st[bc*2+1] = rsqrtf(var + 1e-5f);
  }
}

// ---------------- K4: dsc (NCHW fp32) + dscT/dscL (NHWC bf16 hi/lo) ----------------
__global__ __launch_bounds__(256) void make_dsc(const float* __restrict__ h2,
    const float* __restrict__ st, float* __restrict__ dsc,
    u16* __restrict__ dscT, u16* __restrict__ dscL){
  int blk = blockIdx.x;
  int pt = blk % 144; int r = blk/144; int ch = r & 1; int b = r >> 1;
  int c0 = ch*64, pbase = pt*64;
  __shared__ float tile[64][65];
  int tr = threadIdx.x >> 2;
  int g  = threadIdx.x & 3;
  int c  = c0 + tr;
  float mu = st[(b*128+c)*2];
  float rs = st[(b*128+c)*2+1];
  const float* src = h2 + (size_t)(b*128+c)*HW + pbase + g*16;
  float* d = dsc + (size_t)(b*128+c)*HW + pbase + g*16;
  #pragma unroll
  for (int i=0;i<4;i++){
    float4 v = *(const float4*)(src + i*4);
    v.x=(v.x-mu)*rs; v.y=(v.y-mu)*rs; v.z=(v.z-mu)*rs; v.w=(v.w-mu)*rs;
    *(float4*)(d + i*4) = v;
    tile[tr][g*16+i*4+0]=v.x; tile[tr][g*16+i*4+1]=v.y;
    tile[tr][g*16+i*4+2]=v.z; tile[tr][g*16+i*4+3]=v.w;
  }
  __syncthreads();
  int pr = tr;
  u16* dt = dscT + ((size_t)b*HW + pbase + pr)*NC + c0 + g*16;
  u16* dl = dscL + ((size_t)b*HW + pbase + pr)*NC + c0 + g*16;
  #pragma unroll
  for (int i=0;i<4;i++){
    float v0 = tile[g*16+i*4+0][pr], v1 = tile[g*16+i*4+1][pr];
    float v2 = tile[g*16+i*4+2][pr], v3 = tile[g*16+i*4+3][pr];
    ushort4 hi = make_ushort4(f2b(v0), f2b(v1), f2b(v2), f2b(v3));
    ushort4 lo = make_ushort4(f2b(v0-bu2f(hi.x)), f2b(v1-bu2f(hi.y)),
                              f2b(v2-bu2f(hi.z)), f2b(v3-bu2f(hi.w)));
    *(ushort4*)(dt + i*4) = hi;
    *(ushort4*)(dl + i*4) = lo;
  }
}

// ---------------- K5: offset conv via MFMA, barrier-free per-lane im2col ----------------
// Each lane owns its A-fragment: row = w*16+ln (pixel), channels q*8.. within 32-chunk.
// B (wob, 72KB) is L2-hot; read per-lane. 2-deep register pipeline, full unroll.
__global__ __launch_bounds__(256) void off_mfma(const u16* __restrict__ dscT,
    const u16* __restrict__ dscL, const u16* __restrict__ wob,
    const float* __restrict__ off_b, float4* __restrict__ wg, ushort4* __restrict__ ad){
  __shared__ float Po[18*64];
  int blk = blockIdx.x; int row0 = blk*64;
  int b = rfl(row0/HW); int pbase = rfl(row0 - b*HW);
  int t = threadIdx.x;
  int w = rfl(t>>6); int l = t&63; int q = l>>4; int ln = l&15;
  int P = pbase + w*16 + ln;
  int py = P/96, px_ = P - 96*(P/96);
  const u16* hib = dscT + (size_t)b*HW*NC;
  const u16* lob = dscL + (size_t)b*HW*NC;
  int offs[9];
  #pragma unroll
  for (int k=0;k<9;k++){
    int y2 = py + k/3 - 1, x2 = px_ + k%3 - 1;
    bool valid = ((unsigned)y2 < 96u) && ((unsigned)x2 < 96u);
    offs[k] = valid ? ((y2*96 + x2)*NC) : -1;
  }
  v4f acc0 = (v4f){0.f,0.f,0.f,0.f}, acc1 = (v4f){0.f,0.f,0.f,0.f};
  uint4 rhA,rlA,b0A,b1A, rhB,rlB,b0B,b1B;
  const uint4 Z = (uint4){0,0,0,0};
  auto loadA = [&](int s, uint4& rh, uint4& rl){
    int k = s>>2; int cs = ((s&3)<<5) + q*8;
    int o = offs[k];
    rh = (o>=0) ? *(const uint4*)(hib + o + cs) : Z;
    rl = (o>=0) ? *(const uint4*)(lob + o + cs) : Z;
  };
  auto loadB = [&](int s, uint4& b0, uint4& b1){
    const u16* wp = wob + s*32 + q*8;
    b0 = *(const uint4*)(wp + ln*1152);
    b1 = *(const uint4*)(wp + (16+ln)*1152);
  };
  auto mm = [&](uint4& rh, uint4& rl, uint4& b0, uint4& b1){
    short8 ah = *(short8*)&rh, al = *(short8*)&rl;
    short8 v0 = *(short8*)&b0, v1 = *(short8*)&b1;
    acc0 = __builtin_amdgcn_mfma_f32_16x16x32_bf16(ah, v0, acc0, 0,0,0);
    acc1 = __builtin_amdgcn_mfma_f32_16x16x32_bf16(ah, v1, acc1, 0,0,0);
    acc0 = __builtin_amdgcn_mfma_f32_16x16x32_bf16(al, v0, acc0, 0,0,0);
    acc1 = __builtin_amdgcn_mfma_f32_16x16x32_bf16(al, v1, acc1, 0,0,0);
  };
  loadA(0,rhA,rlA); loadB(0,b0A,b1A);
  #pragma unroll
  for (int s=0;s<36;s+=2){
    loadA(s+1,rhB,rlB); loadB(s+1,b0B,b1B);
    mm(rhA,rlA,b0A,b1A);
    if (s+2<36){ loadA(s+2,rhA,rlA); loadB(s+2,b0A,b1A); }
    mm(rhB,rlB,b0B,b1B);
  }
  #pragma unroll
  for (int nt=0;nt<2;nt++){
    int o = nt*16 + ln;
    if (o < 18){
      float ob = off_b[o];
      v4f a = nt ? acc1 : acc0;
      #pragma unroll
      for (int r=0;r<4;r++) Po[o*64 + w*16 + q*4 + r] = a[r] + ob;
    }
  }
  __syncthreads();
  #pragma unroll
  for (int i=0;i<3;i++){
    int idx = i*256 + t;
    if (idx < 576){
      int pxl = idx & 63, k = idx >> 6;
      int Pp = pbase + pxl;
      float dy = Po[(2*k)*64 + pxl], dx = Po[(2*k+1)*64 + pxl];
      float ys = (float)(Pp/96 + k/3 - 1) + dy;
      float xs = (float)(Pp%96 + k%3 - 1) + dx;
      float fy0 = floorf(ys), fx0 = floorf(xs);
      float wy = ys - fy0, wx = xs - fx0;
      int y0 = (int)fy0, x0 = (int)fx0;
      int y1 = y0+1, x1 = x0+1;
      float vy0 = (y0>=0 && y0<=95) ? 1.f : 0.f;
      float vy1 = (y1>=0 && y1<=95) ? 1.f : 0.f;
      float vx0 = (x0>=0 && x0<=95) ? 1.f : 0.f;
      float vx1 = (x1>=0 && x1<=95) ? 1.f : 0.f;
      int y0c=min(max(y0,0),95), y1c=min(max(y1,0),95);
      int x0c=min(max(x0,0),95), x1c=min(max(x1,0),95);
      float4 w4;
      w4.x = (1.f-wy)*(1.f-wx)*vy0*vx0;
      w4.y = (1.f-wy)*wx*vy0*vx1;
      w4.z = wy*(1.f-wx)*vy1*vx0;
      w4.w = wy*wx*vy1*vx1;
      int gi = (b*9 + k)*HW + pbase + pxl;
      wg[gi] = w4;
      ad[gi] = make_ushort4((u16)(y0c*WD+x0c), (u16)(y0c*WD+x1c),
                            (u16)(y1c*WD+x0c), (u16)(y1c*WD+x1c));
    }
  }
}

// ---------------- K6: deform conv: per-lane gather+combine into A-regs, B in dbuf LDS ----
// One barrier per K-step (36 total). A never touches LDS. B stride 44 shorts (<=2-way banks).
__global__ __launch_bounds__(256) void deform_mfma(const u16* __restrict__ dscT,
    const u16* __restrict__ wdcb, const float* __restrict__ dc_b,
    const float4* __restrict__ wg, const ushort4* __restrict__ ad,
    float* __restrict__ dc_t){
  __shared__ short Bs[2][5632];               // 2 x 128 rows x 44 shorts
  int blk = blockIdx.x; int row0 = blk*64;
  int b = rfl(row0/HW); int pbase = rfl(row0 - b*HW);
  int t = threadIdx.x;
  int w = rfl(t>>6); int l = t&63; int q = l>>4; int ln = l&15;
  int P = pbase + w*16 + ln;
  const u16* db0 = dscT + (size_t)b*HW*NC;
  int br0 = t>>2, bsg = (t&3)*8;              // B staging: 2 rows x 16B per thread
  uint4 r0,r1,r2,r3, wbv0, wbv1;
  auto loadB = [&](int s){
    const u16* wp = wdcb + s*32 + bsg;
    wbv0 = *(const uint4*)(wp + br0*1152);
    wbv1 = *(const uint4*)(wp + (64+br0)*1152);
  };
  auto commitB = [&](int buf){
    *(uint4*)&Bs[buf][br0*44 + bsg] = wbv0;
    *(uint4*)&Bs[buf][(64+br0)*44 + bsg] = wbv1;
  };
  auto loadA = [&](int cseg, const ushort4 a){
    const u16* db = db0 + (cseg<<5) + q*8;
    r0 = *(const uint4*)(db + ((int)a.x << 7));
    r1 = *(const uint4*)(db + ((int)a.y << 7));
    r2 = *(const uint4*)(db + ((int)a.z << 7));
    r3 = *(const uint4*)(db + ((int)a.w << 7));
  };
  auto combineA = [&](const float4 wvk)->short8{
    const u16* pa=(const u16*)&r0; const u16* pb=(const u16*)&r1;
    const u16* pc=(const u16*)&r2; const u16* pd=(const u16*)&r3;
    short8 sv;
    #pragma unroll
    for (int j=0;j<8;j++){
      float f = wvk.x*bu2f(pa[j]) + wvk.y*bu2f(pb[j]) + wvk.z*bu2f(pc[j]) + wvk.w*bu2f(pd[j]);
      sv[j] = (short)f2b(f);
    }
    return sv;
  };
  v4f acc[8];
  #pragma unroll
  for (int nt=0;nt<8;nt++) acc[nt] = (v4f){0.f,0.f,0.f,0.f};
  auto mm8 = [&](short8 af, int buf){
    #pragma unroll
    for (int nt=0;nt<8;nt++){
      short8 bf = *(short8*)&Bs[buf][(nt*16+ln)*44 + q*8];
      acc[nt] = __builtin_amdgcn_mfma_f32_16x16x32_bf16(af, bf, acc[nt], 0,0,0);
    }
  };
  float4 wvC, wvN; ushort4 avC, avN;
  { int gi = b*9*HW + P; wvC = wg[gi]; avC = ad[gi]; }
  loadB(0); loadA(0, avC);
  commitB(0);
  short8 afA = combineA(wvC), afB;
  loadB(1); loadA(1, avC);
  __syncthreads();
  #pragma unroll 1
  for (int k=0;k<9;k++){
    int s0 = k*4;
    bool more = (k<8);
    if (more){ int gi = (b*9 + k+1)*HW + P; wvN = wg[gi]; avN = ad[gi]; }
    // step s0 (buf0)
    commitB(1); loadB(s0+2);
    mm8(afA, 0);
    afB = combineA(wvC); loadA(2, avC);
    __syncthreads();
    // step s0+1 (buf1)
    commitB(0); loadB(s0+3);
    mm8(afB, 1);
    afA = combineA(wvC); loadA(3, avC);
    __syncthreads();
    // step s0+2 (buf0)
    commitB(1); if (more) loadB(s0+4);
    mm8(afA, 0);
    afB = combineA(wvC); if (more) loadA(0, avN);
    __syncthreads();
    // step s0+3 (buf1)
    if (more){ commitB(0); loadB(s0+5); }
    mm8(afB, 1);
    if (more){ afA = combineA(wvN); loadA(1, avN); }
    __syncthreads();
    if (more){ wvC = wvN; avC = avN; }
  }
  #pragma unroll
  for (int nt=0;nt<8;nt++){
    int o = nt*16 + ln;
    float bias = dc_b[o];
    #pragma unroll
    for (int r=0;r<4;r++){
      int px = pbase + w*16 + q*4 + r;
      dc_t[((size_t)b*HW + px)*NC + o] = acc[nt][r] + bias;
    }
  }
}

// ---------------- K7: channel LayerNorm + sigmoid gate + multiply ----------------
__global__ __launch_bounds__(256) void epilogue(const float* __restrict__ dc_t,
    const float* __restrict__ dsc, const float* __restrict__ ln_g,
    const float* __restrict__ ln_b, float* __restrict__ out){
  __shared__ float T[64*129];
  __shared__ float Ps[4*64], Qs[4*64], Ms[64], Rs[64];
  int blk = blockIdx.x;
  int b = rfl(blk/144); int pbase = rfl(blk - (blk/144)*144)*64;
  int t = threadIdx.x;
  #pragma unroll
  for (int i=0;i<8;i++){
    int idx = i*256 + t; int px = idx>>5, seg = idx&31;
    float4 v = *(const float4*)(dc_t + ((size_t)b*HW + pbase + px)*NC + seg*4);
    float* d = &T[px*129 + seg*4];
    d[0]=v.x; d[1]=v.y; d[2]=v.z; d[3]=v.w;
  }
  __syncthreads();
  int px = t&63, cg = t>>6;
  float s=0.f, ss=0.f;
  #pragma unroll
  for (int i=0;i<32;i++){ float v = T[px*129 + cg*32 + i]; s += v; ss = fmaf(v,v,ss); }
  Ps[cg*64+px] = s; Qs[cg*64+px] = ss;
  __syncthreads();
  if (t<64){
    float S = Ps[px]+Ps[64+px]+Ps[128+px]+Ps[192+px];
    float SS= Qs[px]+Qs[64+px]+Qs[128+px]+Qs[192+px];
    float m = S*(1.f/128.f);
    float var = SS*(1.f/128.f) - m*m;
    Ms[px] = m; Rs[px] = rsqrtf(var + 1e-5f);
  }
  __syncthreads();
  float m = Ms[px], rs = Rs[px];
  #pragma unroll 4
  for (int i=0;i<32;i++){
    int c = cg*32 + i;
    float ln = (T[px*129+c] - m)*rs*ln_g[c] + ln_b[c];
    float attn = 1.f/(1.f+__expf(-ln));
    size_t idx = (size_t)(b*NC+c)*HW + pbase + px;
    out[idx] = dsc[idx]*attn;
  }
}

extern "C" void kernel_launch(void* const* d_in, const int* in_sizes, int n_in,
                              void* d_out, int out_size, void* d_ws, size_t ws_size,
                              hipStream_t stream){
  const float* x    = (const float*)d_in[0];
  const float* dw_w = (const float*)d_in[1];
  const float* dw_b = (const float*)d_in[2];
  const float* pw_w = (const float*)d_in[3];
  const float* pw_b = (const float*)d_in[4];
  const float* off_w= (const float*)d_in[5];
  const float* off_b= (const float*)d_in[6];
  const float* dc_w = (const float*)d_in[7];
  const float* dc_b = (const float*)d_in[8];
  const float* ln_g = (const float*)d_in[9];
  const float* ln_b = (const float*)d_in[10];
  float* out = (float*)d_out;

  float* W    = (float*)d_ws;
  float*   bufA = W;                          // h1, then dsc (NCHW f32)
  float*   bufB = W + 4718592;                // h2, then dc_t (NHWC f32)
  u16*     dscT = (u16*)(W + 9437184);        // NHWC bf16 hi (4718592 u16)
  u16*     dscL = (u16*)(W + 11796480);       // NHWC bf16 lo residual
  float4*  wg   = (float4*)(W + 14155776);    // 331776 float4
  ushort4* ad   = (ushort4*)(W + 15482880);   // 331776 ushort4
  float*   st   = W + 16146432;
  u16*     wpwb = (u16*)(W + 16147456);       // 16384 u16
  u16*     wob  = (u16*)(W + 16155648);       // 36864 u16
  u16*     wdcb = (u16*)(W + 16174080);       // 147456 u16

  prep_weights<<<576, 256, 0, stream>>>(pw_w, off_w, dc_w, wpwb, wob, wdcb);
  dw_conv     <<<18432, 256, 0, stream>>>(x, dw_w, dw_b, bufA);
  pw_mfma     <<<576, 256, 0, stream>>>(bufA, wpwb, pw_b, bufB);
  inorm_stats <<<512, 256, 0, stream>>>(bufB, st);
  make_dsc    <<<1152, 256, 0, stream>>>(bufB, st, bufA, dscT, dscL);
  off_mfma    <<<576, 256, 0, stream>>>(dscT, dscL, wob, off_b, wg, ad);
  deform_mfma <<<576, 256, 0, stream>>>(dscT, wdcb, dc_b, wg, ad, bufB);
  epilogue    <<<576, 256, 0, stream>>>(bufB, bufA, ln_g, ln_b, out);
}

// Round 4
// 261.434 us; speedup vs baseline: 1.0516x; 1.0516x over previous
//
#include <hip/hip_runtime.h>
#include <math.h>

#define HW 9216
#define WD 96
#define NC 128

typedef unsigned short u16;
typedef __attribute__((ext_vector_type(8))) short short8;
typedef __attribute__((ext_vector_type(4))) float v4f;

__device__ __forceinline__ int rfl(int v){ return __builtin_amdgcn_readfirstlane(v); }
__device__ __forceinline__ float bu2f(u16 s){ return __uint_as_float(((unsigned)s)<<16); }
__device__ __forceinline__ u16 f2b(float f){ unsigned u = __float_as_uint(f);
  return (u16)((u + 0x7fffu + ((u>>16)&1u))>>16); }

// ---------------- K0: weight prep ----------------
__global__ __launch_bounds__(256) void prep_weights(const float* __restrict__ pw_w,
    const float* __restrict__ off_w, const float* __restrict__ dc_w,
    u16* __restrict__ wpwb, u16* __restrict__ wob, u16* __restrict__ wdcb){
  int t = blockIdx.x*256 + threadIdx.x;
  if (t < 16384) wpwb[t] = f2b(pw_w[t]);
  if (t < 36864){ int o = t/1152, r = t - o*1152; int k = r>>7, c = r&127;
                  wob[t] = (o<18) ? f2b(off_w[(o*128+c)*9+k]) : (u16)0; }
  if (t < 147456){ int o = t/1152, r = t - o*1152; int k = r>>7, c = r&127;
                   wdcb[t] = f2b(dc_w[(o*128+c)*9 + k]); }
}

// ---------------- K1: depthwise 3x3 + bias (NCHW fp32) ----------------
__global__ __launch_bounds__(256) void dw_conv(const float* __restrict__ x,
    const float* __restrict__ w, const float* __restrict__ bias, float* __restrict__ h1){
  int n = blockIdx.x*256 + threadIdx.x;
  int bc = rfl(n / HW);
  int p = n - bc*HW;
  int c = bc & 127;
  int yy = p / WD, xx = p - (p/WD)*WD;
  const float* xc = x + (size_t)bc*HW;
  float acc = bias[c];
  #pragma unroll
  for (int r=0;r<3;r++){
    int y2 = yy + r - 1;
    #pragma unroll
    for (int cc2=0;cc2<3;cc2++){
      int x2 = xx + cc2 - 1;
      if (y2>=0 && y2<96 && x2>=0 && x2<96)
        acc = fmaf(w[c*9 + r*3 + cc2], xc[y2*WD + x2], acc);
    }
  }
  h1[n] = acc;
}

// ---------------- K2: pointwise 1x1 via MFMA ----------------
__global__ __launch_bounds__(256) void pw_mfma(const float* __restrict__ h1,
    const u16* __restrict__ wpwb, const float* __restrict__ pw_b, float* __restrict__ h2){
  __shared__ short Aw[128*136];
  __shared__ short Bw[128*68];
  int blk = blockIdx.x; int row0 = blk*64;
  int b = rfl(row0/HW); int pbase = rfl(row0 - b*HW);
  int t = threadIdx.x;
  #pragma unroll
  for (int i=0;i<8;i++){
    int idx = i*256 + t; int o = idx>>4, seg = idx&15;
    *(short8*)&Aw[o*136 + seg*8] = *(const short8*)(wpwb + o*128 + seg*8);
  }
  #pragma unroll
  for (int i=0;i<8;i++){
    int idx = i*256 + t; int c = idx>>4, seg = idx&15;
    float4 v = *(const float4*)(h1 + (size_t)(b*NC+c)*HW + pbase + seg*4);
    ushort4 pk = make_ushort4(f2b(v.x), f2b(v.y), f2b(v.z), f2b(v.w));
    *(ushort4*)&Bw[c*68 + seg*4] = pk;
  }
  __syncthreads();
  int w = rfl(t>>6); int l = t&63; int q = l>>4; int ln = l&15;
  v4f acc[8];
  #pragma unroll
  for (int mt=0;mt<8;mt++) acc[mt] = (v4f){0.f,0.f,0.f,0.f};
  #pragma unroll
  for (int ks=0;ks<4;ks++){
    short8 bf;
    #pragma unroll
    for (int j=0;j<8;j++) bf[j] = Bw[(ks*32 + q*8 + j)*68 + w*16 + ln];
    #pragma unroll
    for (int mt=0;mt<8;mt++){
      short8 af = *(short8*)&Aw[(mt*16+ln)*136 + ks*32 + q*8];
      acc[mt] = __builtin_amdgcn_mfma_f32_16x16x32_bf16(af, bf, acc[mt], 0,0,0);
    }
  }
  int px = pbase + w*16 + ln;
  #pragma unroll
  for (int mt=0;mt<8;mt++){
    #pragma unroll
    for (int r=0;r<4;r++){
      int o = mt*16 + q*4 + r;
      h2[(size_t)(b*NC+o)*HW + px] = acc[mt][r] + pw_b[o];
    }
  }
}

// ---------------- K3: InstanceNorm stats ----------------
__global__ __launch_bounds__(256) void inorm_stats(const float* __restrict__ h2, float* __restrict__ st){
  int bc = blockIdx.x;
  const float* src = h2 + (size_t)bc*HW;
  float s=0.f, ss=0.f;
  for (int i=threadIdx.x; i<HW; i+=256){ float v=src[i]; s+=v; ss=fmaf(v,v,ss); }
  #pragma unroll
  for (int off=32; off; off>>=1){ s += __shfl_down(s,off); ss += __shfl_down(ss,off); }
  __shared__ float rsm[2][4];
  int wave = threadIdx.x>>6, lane = threadIdx.x&63;
  if (lane==0){ rsm[0][wave]=s; rsm[1][wave]=ss; }
  __syncthreads();
  if (threadIdx.x==0){
    float S = rsm[0][0]+rsm[0][1]+rsm[0][2]+rsm[0][3];
    float SS= rsm[1][0]+rsm[1][1]+rsm[1][2]+rsm[1][3];
    float mu = S * (1.f/9216.f);
    float var = SS * (1.f/9216.f) - mu*mu;
    st[bc*2]   = mu;
    st[bc*2+1] = rsqrtf(var + 1e-5f);
  }
}

// ---------------- K4: dsc (NCHW fp32) + dscT/dscL (NHWC bf16 hi/lo) ----------------
__global__ __launch_bounds__(256) void make_dsc(const float* __restrict__ h2,
    const float* __restrict__ st, float* __restrict__ dsc,
    u16* __restrict__ dscT, u16* __restrict__ dscL){
  int blk = blockIdx.x;
  int pt = blk % 144; int r = blk/144; int ch = r & 1; int b = r >> 1;
  int c0 = ch*64, pbase = pt*64;
  __shared__ float tile[64][65];
  int tr = threadIdx.x >> 2;
  int g  = threadIdx.x & 3;
  int c  = c0 + tr;
  float mu = st[(b*128+c)*2];
  float rs = st[(b*128+c)*2+1];
  const float* src = h2 + (size_t)(b*128+c)*HW + pbase + g*16;
  float* d = dsc + (size_t)(b*128+c)*HW + pbase + g*16;
  #pragma unroll
  for (int i=0;i<4;i++){
    float4 v = *(const float4*)(src + i*4);
    v.x=(v.x-mu)*rs; v.y=(v.y-mu)*rs; v.z=(v.z-mu)*rs; v.w=(v.w-mu)*rs;
    *(float4*)(d + i*4) = v;
    tile[tr][g*16+i*4+0]=v.x; tile[tr][g*16+i*4+1]=v.y;
    tile[tr][g*16+i*4+2]=v.z; tile[tr][g*16+i*4+3]=v.w;
  }
  __syncthreads();
  int pr = tr;
  u16* dt = dscT + ((size_t)b*HW + pbase + pr)*NC + c0 + g*16;
  u16* dl = dscL + ((size_t)b*HW + pbase + pr)*NC + c0 + g*16;
  #pragma unroll
  for (int i=0;i<4;i++){
    float v0 = tile[g*16+i*4+0][pr], v1 = tile[g*16+i*4+1][pr];
    float v2 = tile[g*16+i*4+2][pr], v3 = tile[g*16+i*4+3][pr];
    ushort4 hi = make_ushort4(f2b(v0), f2b(v1), f2b(v2), f2b(v3));
    ushort4 lo = make_ushort4(f2b(v0-bu2f(hi.x)), f2b(v1-bu2f(hi.y)),
                              f2b(v2-bu2f(hi.z)), f2b(v3-bu2f(hi.w)));
    *(ushort4*)(dt + i*4) = hi;
    *(ushort4*)(dl + i*4) = lo;
  }
}

// ---------------- K5: offset conv via MFMA (round-0 structure) + fused bilinear precomp ----
__global__ __launch_bounds__(256) void off_mfma(const u16* __restrict__ dscT,
    const u16* __restrict__ dscL, const u16* __restrict__ wob,
    const float* __restrict__ off_b, float4* __restrict__ wg, ushort4* __restrict__ ad){
  __shared__ short As[2][64*40];             // hi/lo A tiles (64 px x 32 K), pad 40
  __shared__ short Bs[32*40];                // W tile (32 o x 32 K)
  __shared__ float Po[18*64];                // offsets [o][px]
  int blk = blockIdx.x; int row0 = blk*64;   // 576 blocks
  int b = rfl(row0/HW); int pbase = rfl(row0 - b*HW);
  int t = threadIdx.x;
  int apx = t>>2, aseg = t&3;                // A staging: pixel, 8-ch group
  int bo = t>>3, bseg = t&7;                 // B staging: o row, 4-k group
  int w = rfl(t>>6); int l = t&63; int q = l>>4; int ln = l&15;
  int P = pbase + apx;
  int py = P/96, px_ = P - 96*(P/96);
  const u16* hib = dscT + (size_t)b*HW*NC;
  const u16* lob = dscL + (size_t)b*HW*NC;
  uint4 rh, rl; ushort4 wb;
  auto prefetch = [&](int s){
    int k = s>>2, cseg = s&3;
    int y2 = py + k/3 - 1, x2 = px_ + k%3 - 1;
    bool valid = ((unsigned)y2 < 96u) && ((unsigned)x2 < 96u);
    int off = ((y2*96 + x2)*NC) + cseg*32 + aseg*8;
    rh = valid ? *(const uint4*)(hib + off) : (uint4){0,0,0,0};
    rl = valid ? *(const uint4*)(lob + off) : (uint4){0,0,0,0};
    wb = *(const ushort4*)(wob + bo*1152 + k*128 + cseg*32 + bseg*4);
  };
  auto commit = [&](){
    *(short8*)&As[0][apx*40 + aseg*8] = *(short8*)&rh;
    *(short8*)&As[1][apx*40 + aseg*8] = *(short8*)&rl;
    *(ushort4*)&Bs[bo*40 + bseg*4] = wb;
  };
  v4f acc[2];
  acc[0] = (v4f){0.f,0.f,0.f,0.f}; acc[1] = (v4f){0.f,0.f,0.f,0.f};
  prefetch(0); commit();
  __syncthreads();
  #pragma unroll 1
  for (int s=0;s<36;s++){
    if (s<35) prefetch(s+1);
    short8 ah = *(short8*)&As[0][(w*16+ln)*40 + q*8];
    short8 al = *(short8*)&As[1][(w*16+ln)*40 + q*8];
    short8 b0 = *(short8*)&Bs[ln*40 + q*8];
    short8 b1 = *(short8*)&Bs[(16+ln)*40 + q*8];
    acc[0] = __builtin_amdgcn_mfma_f32_16x16x32_bf16(ah, b0, acc[0], 0,0,0);
    acc[1] = __builtin_amdgcn_mfma_f32_16x16x32_bf16(ah, b1, acc[1], 0,0,0);
    acc[0] = __builtin_amdgcn_mfma_f32_16x16x32_bf16(al, b0, acc[0], 0,0,0);
    acc[1] = __builtin_amdgcn_mfma_f32_16x16x32_bf16(al, b1, acc[1], 0,0,0);
    __syncthreads();
    if (s<35){ commit(); __syncthreads(); }
  }
  #pragma unroll
  for (int nt=0;nt<2;nt++){
    int o = nt*16 + ln;
    if (o < 18){
      float ob = off_b[o];
      #pragma unroll
      for (int r=0;r<4;r++) Po[o*64 + w*16 + q*4 + r] = acc[nt][r] + ob;
    }
  }
  __syncthreads();
  #pragma unroll
  for (int i=0;i<3;i++){
    int idx = i*256 + t;
    if (idx < 576){
      int pxl = idx & 63, k = idx >> 6;
      int Pp = pbase + pxl;
      float dy = Po[(2*k)*64 + pxl], dx = Po[(2*k+1)*64 + pxl];
      float ys = (float)(Pp/96 + k/3 - 1) + dy;
      float xs = (float)(Pp%96 + k%3 - 1) + dx;
      float fy0 = floorf(ys), fx0 = floorf(xs);
      float wy = ys - fy0, wx = xs - fx0;
      int y0 = (int)fy0, x0 = (int)fx0;
      int y1 = y0+1, x1 = x0+1;
      float vy0 = (y0>=0 && y0<=95) ? 1.f : 0.f;
      float vy1 = (y1>=0 && y1<=95) ? 1.f : 0.f;
      float vx0 = (x0>=0 && x0<=95) ? 1.f : 0.f;
      float vx1 = (x1>=0 && x1<=95) ? 1.f : 0.f;
      int y0c=min(max(y0,0),95), y1c=min(max(y1,0),95);
      int x0c=min(max(x0,0),95), x1c=min(max(x1,0),95);
      float4 w4;
      w4.x = (1.f-wy)*(1.f-wx)*vy0*vx0;
      w4.y = (1.f-wy)*wx*vy0*vx1;
      w4.z = wy*(1.f-wx)*vy1*vx0;
      w4.w = wy*wx*vy1*vx1;
      int gi = (b*9 + k)*HW + pbase + pxl;
      wg[gi] = w4;
      ad[gi] = make_ushort4((u16)(y0c*WD+x0c), (u16)(y0c*WD+x1c),
                            (u16)(y1c*WD+x0c), (u16)(y1c*WD+x1c));
    }
  }
}

// ---------------- K6: deform conv, round-0 structure + output-channel split ----------------
// 1152 blocks: tile = (blk>>4)*8 + (blk&7), kk = (blk>>3)&1 selects 64 output channels.
// Sibling blocks (kk=0,1) share the same tile's A-gather and land on the same XCD
// (both have blockIdx % 8 equal), one dispatch round apart -> second gather is L2-hot.
__global__ __launch_bounds__(256) void deform_mfma(const u16* __restrict__ dscT,
    const u16* __restrict__ wdcb, const float* __restrict__ dc_b,
    const float4* __restrict__ wg, const ushort4* __restrict__ ad,
    float* __restrict__ dc_t){
  __shared__ short As[64*40];
  __shared__ short Bs[64*40];
  int blk = blockIdx.x;
  int tile = (blk>>4)*8 + (blk&7);
  int kk = (blk>>3)&1;
  int row0 = tile*64;
  int b = rfl(row0/HW); int pbase = rfl(row0 - b*HW);
  int t = threadIdx.x;
  int am = t>>2, aseg = t&3;
  int o0 = t>>2, bseg = t&3;
  int w = rfl(t>>6); int l = t&63; int q = l>>4; int ln = l&15;
  const u16* db0 = dscT + (size_t)b*HW*NC;
  const u16* wbase = wdcb + (size_t)(kk*64)*1152;
  float4 wv; ushort4 av; uint4 r0,r1,r2,r3, wb0;
  auto prefetch = [&](int s){
    int k = s>>2; int cs = ((s&3)<<5) + aseg*8;
    int wgi = (b*9 + k)*HW + pbase + am;
    wv = wg[wgi]; av = ad[wgi];
    const u16* db = db0 + cs;
    r0 = *(const uint4*)(db + (int)av.x*NC);
    r1 = *(const uint4*)(db + (int)av.y*NC);
    r2 = *(const uint4*)(db + (int)av.z*NC);
    r3 = *(const uint4*)(db + (int)av.w*NC);
    wb0 = *(const uint4*)(wbase + o0*1152 + s*32 + bseg*8);
  };
  auto commit = [&](){
    const u16* pa=(const u16*)&r0; const u16* pb=(const u16*)&r1;
    const u16* pc=(const u16*)&r2; const u16* pd=(const u16*)&r3;
    short8 sv;
    #pragma unroll
    for (int j=0;j<8;j++){
      float f = wv.x*bu2f(pa[j]) + wv.y*bu2f(pb[j]) + wv.z*bu2f(pc[j]) + wv.w*bu2f(pd[j]);
      sv[j] = (short)f2b(f);
    }
    *(short8*)&As[am*40 + aseg*8] = sv;
    *(short8*)&Bs[o0*40 + bseg*8] = *(short8*)&wb0;
  };
  v4f acc[4];
  #pragma unroll
  for (int nt=0;nt<4;nt++) acc[nt] = (v4f){0.f,0.f,0.f,0.f};
  prefetch(0); commit();
  __syncthreads();
  #pragma unroll 1
  for (int s=0;s<36;s++){
    if (s<35) prefetch(s+1);
    short8 af = *(short8*)&As[(w*16+ln)*40 + q*8];
    #pragma unroll
    for (int nt=0;nt<4;nt++){
      short8 bf = *(short8*)&Bs[(nt*16+ln)*40 + q*8];
      acc[nt] = __builtin_amdgcn_mfma_f32_16x16x32_bf16(af, bf, acc[nt], 0,0,0);
    }
    __syncthreads();
    if (s<35){ commit(); __syncthreads(); }
  }
  #pragma unroll
  for (int nt=0;nt<4;nt++){
    int o = kk*64 + nt*16 + ln;
    float bias = dc_b[o];
    #pragma unroll
    for (int r=0;r<4;r++){
      int px = pbase + w*16 + q*4 + r;
      dc_t[((size_t)b*HW + px)*NC + o] = acc[nt][r] + bias;
    }
  }
}

// ---------------- K7: channel LayerNorm + sigmoid gate + multiply ----------------
__global__ __launch_bounds__(256) void epilogue(const float* __restrict__ dc_t,
    const float* __restrict__ dsc, const float* __restrict__ ln_g,
    const float* __restrict__ ln_b, float* __restrict__ out){
  __shared__ float T[64*129];
  __shared__ float Ps[4*64], Qs[4*64], Ms[64], Rs[64];
  int blk = blockIdx.x;
  int b = rfl(blk/144); int pbase = rfl(blk - (blk/144)*144)*64;
  int t = threadIdx.x;
  #pragma unroll
  for (int i=0;i<8;i++){
    int idx = i*256 + t; int px = idx>>5, seg = idx&31;
    float4 v = *(const float4*)(dc_t + ((size_t)b*HW + pbase + px)*NC + seg*4);
    float* d = &T[px*129 + seg*4];
    d[0]=v.x; d[1]=v.y; d[2]=v.z; d[3]=v.w;
  }
  __syncthreads();
  int px = t&63, cg = t>>6;
  float s=0.f, ss=0.f;
  #pragma unroll
  for (int i=0;i<32;i++){ float v = T[px*129 + cg*32 + i]; s += v; ss = fmaf(v,v,ss); }
  Ps[cg*64+px] = s; Qs[cg*64+px] = ss;
  __syncthreads();
  if (t<64){
    float S = Ps[px]+Ps[64+px]+Ps[128+px]+Ps[192+px];
    float SS= Qs[px]+Qs[64+px]+Qs[128+px]+Qs[192+px];
    float m = S*(1.f/128.f);
    float var = SS*(1.f/128.f) - m*m;
    Ms[px] = m; Rs[px] = rsqrtf(var + 1e-5f);
  }
  __syncthreads();
  float m = Ms[px], rs = Rs[px];
  #pragma unroll 4
  for (int i=0;i<32;i++){
    int c = cg*32 + i;
    float ln = (T[px*129+c] - m)*rs*ln_g[c] + ln_b[c];
    float attn = 1.f/(1.f+__expf(-ln));
    size_t idx = (size_t)(b*NC+c)*HW + pbase + px;
    out[idx] = dsc[idx]*attn;
  }
}

extern "C" void kernel_launch(void* const* d_in, const int* in_sizes, int n_in,
                              void* d_out, int out_size, void* d_ws, size_t ws_size,
                              hipStream_t stream){
  const float* x    = (const float*)d_in[0];
  const float* dw_w = (const float*)d_in[1];
  const float* dw_b = (const float*)d_in[2];
  const float* pw_w = (const float*)d_in[3];
  const float* pw_b = (const float*)d_in[4];
  const float* off_w= (const float*)d_in[5];
  const float* off_b= (const float*)d_in[6];
  const float* dc_w = (const float*)d_in[7];
  const float* dc_b = (const float*)d_in[8];
  const float* ln_g = (const float*)d_in[9];
  const float* ln_b = (const float*)d_in[10];
  float* out = (float*)d_out;

  float* W    = (float*)d_ws;
  float*   bufA = W;                          // h1, then dsc (NCHW f32)
  float*   bufB = W + 4718592;                // h2, then dc_t (NHWC f32)
  u16*     dscT = (u16*)(W + 9437184);        // NHWC bf16 hi (4718592 u16)
  u16*     dscL = (u16*)(W + 11796480);       // NHWC bf16 lo residual
  float4*  wg   = (float4*)(W + 14155776);    // 331776 float4
  ushort4* ad   = (ushort4*)(W + 15482880);   // 331776 ushort4
  float*   st   = W + 16146432;
  u16*     wpwb = (u16*)(W + 16147456);       // 16384 u16
  u16*     wob  = (u16*)(W + 16155648);       // 36864 u16
  u16*     wdcb = (u16*)(W + 16174080);       // 147456 u16

  prep_weights<<<576, 256, 0, stream>>>(pw_w, off_w, dc_w, wpwb, wob, wdcb);
  dw_conv     <<<18432, 256, 0, stream>>>(x, dw_w, dw_b, bufA);
  pw_mfma     <<<576, 256, 0, stream>>>(bufA, wpwb, pw_b, bufB);
  inorm_stats <<<512, 256, 0, stream>>>(bufB, st);
  make_dsc    <<<1152, 256, 0, stream>>>(bufB, st, bufA, dscT, dscL);
  off_mfma    <<<576, 256, 0, stream>>>(dscT, dscL, wob, off_b, wg, ad);
  deform_mfma <<<1152, 256, 0, stream>>>(dscT, wdcb, dc_b, wg, ad, bufB);
  epilogue    <<<576, 256, 0, stream>>>(bufB, bufA, ln_g, ln_b, out);
}

// Round 5
// 242.054 us; speedup vs baseline: 1.1358x; 1.0801x over previous
//
#include <hip/hip_runtime.h>
#include <math.h>

#define HW 9216
#define WD 96
#define NC 128

typedef unsigned short u16;
typedef __attribute__((ext_vector_type(8))) short short8;
typedef __attribute__((ext_vector_type(4))) float v4f;

__device__ __forceinline__ int rfl(int v){ return __builtin_amdgcn_readfirstlane(v); }
__device__ __forceinline__ float bu2f(u16 s){ return __uint_as_float(((unsigned)s)<<16); }
__device__ __forceinline__ u16 f2b(float f){ unsigned u = __float_as_uint(f);
  return (u16)((u + 0x7fffu + ((u>>16)&1u))>>16); }

// ---------------- K0: weight prep ----------------
__global__ __launch_bounds__(256) void prep_weights(const float* __restrict__ pw_w,
    const float* __restrict__ off_w, const float* __restrict__ dc_w,
    u16* __restrict__ wpwb, u16* __restrict__ wob, u16* __restrict__ wdcb){
  int t = blockIdx.x*256 + threadIdx.x;
  if (t < 16384) wpwb[t] = f2b(pw_w[t]);
  if (t < 36864){ int o = t/1152, r = t - o*1152; int k = r>>7, c = r&127;
                  wob[t] = (o<18) ? f2b(off_w[(o*128+c)*9+k]) : (u16)0; }
  if (t < 147456){ int o = t/1152, r = t - o*1152; int k = r>>7, c = r&127;
                   wdcb[t] = f2b(dc_w[(o*128+c)*9 + k]); }
}

// ---------------- K1: depthwise 3x3 + bias (NCHW fp32) ----------------
__global__ __launch_bounds__(256) void dw_conv(const float* __restrict__ x,
    const float* __restrict__ w, const float* __restrict__ bias, float* __restrict__ h1){
  int n = blockIdx.x*256 + threadIdx.x;
  int bc = rfl(n / HW);
  int p = n - bc*HW;
  int c = bc & 127;
  int yy = p / WD, xx = p - (p/WD)*WD;
  const float* xc = x + (size_t)bc*HW;
  float acc = bias[c];
  #pragma unroll
  for (int r=0;r<3;r++){
    int y2 = yy + r - 1;
    #pragma unroll
    for (int cc2=0;cc2<3;cc2++){
      int x2 = xx + cc2 - 1;
      if (y2>=0 && y2<96 && x2>=0 && x2<96)
        acc = fmaf(w[c*9 + r*3 + cc2], xc[y2*WD + x2], acc);
    }
  }
  h1[n] = acc;
}

// ---------------- K2: pointwise 1x1 via MFMA ----------------
__global__ __launch_bounds__(256) void pw_mfma(const float* __restrict__ h1,
    const u16* __restrict__ wpwb, const float* __restrict__ pw_b, float* __restrict__ h2){
  __shared__ short Aw[128*136];
  __shared__ short Bw[128*68];
  int blk = blockIdx.x; int row0 = blk*64;
  int b = rfl(row0/HW); int pbase = rfl(row0 - b*HW);
  int t = threadIdx.x;
  #pragma unroll
  for (int i=0;i<8;i++){
    int idx = i*256 + t; int o = idx>>4, seg = idx&15;
    *(short8*)&Aw[o*136 + seg*8] = *(const short8*)(wpwb + o*128 + seg*8);
  }
  #pragma unroll
  for (int i=0;i<8;i++){
    int idx = i*256 + t; int c = idx>>4, seg = idx&15;
    float4 v = *(const float4*)(h1 + (size_t)(b*NC+c)*HW + pbase + seg*4);
    ushort4 pk = make_ushort4(f2b(v.x), f2b(v.y), f2b(v.z), f2b(v.w));
    *(ushort4*)&Bw[c*68 + seg*4] = pk;
  }
  __syncthreads();
  int w = rfl(t>>6); int l = t&63; int q = l>>4; int ln = l&15;
  v4f acc[8];
  #pragma unroll
  for (int mt=0;mt<8;mt++) acc[mt] = (v4f){0.f,0.f,0.f,0.f};
  #pragma unroll
  for (int ks=0;ks<4;ks++){
    short8 bf;
    #pragma unroll
    for (int j=0;j<8;j++) bf[j] = Bw[(ks*32 + q*8 + j)*68 + w*16 + ln];
    #pragma unroll
    for (int mt=0;mt<8;mt++){
      short8 af = *(short8*)&Aw[(mt*16+ln)*136 + ks*32 + q*8];
      acc[mt] = __builtin_amdgcn_mfma_f32_16x16x32_bf16(af, bf, acc[mt], 0,0,0);
    }
  }
  int px = pbase + w*16 + ln;
  #pragma unroll
  for (int mt=0;mt<8;mt++){
    #pragma unroll
    for (int r=0;r<4;r++){
      int o = mt*16 + q*4 + r;
      h2[(size_t)(b*NC+o)*HW + px] = acc[mt][r] + pw_b[o];
    }
  }
}

// ---------------- K3: InstanceNorm stats ----------------
__global__ __launch_bounds__(256) void inorm_stats(const float* __restrict__ h2, float* __restrict__ st){
  int bc = blockIdx.x;
  const float* src = h2 + (size_t)bc*HW;
  float s=0.f, ss=0.f;
  for (int i=threadIdx.x; i<HW; i+=256){ float v=src[i]; s+=v; ss=fmaf(v,v,ss); }
  #pragma unroll
  for (int off=32; off; off>>=1){ s += __shfl_down(s,off); ss += __shfl_down(ss,off); }
  __shared__ float rsm[2][4];
  int wave = threadIdx.x>>6, lane = threadIdx.x&63;
  if (lane==0){ rsm[0][wave]=s; rsm[1][wave]=ss; }
  __syncthreads();
  if (threadIdx.x==0){
    float S = rsm[0][0]+rsm[0][1]+rsm[0][2]+rsm[0][3];
    float SS= rsm[1][0]+rsm[1][1]+rsm[1][2]+rsm[1][3];
    float mu = S * (1.f/9216.f);
    float var = SS * (1.f/9216.f) - mu*mu;
    st[bc*2]   = mu;
    st[bc*2+1] = rsqrtf(var + 1e-5f);
  }
}

// ---------------- K4: dsc (NCHW fp32) + dscT/dscL (NHWC bf16 hi/lo) ----------------
__global__ __launch_bounds__(256) void make_dsc(const float* __restrict__ h2,
    const float* __restrict__ st, float* __restrict__ dsc,
    u16* __restrict__ dscT, u16* __restrict__ dscL){
  int blk = blockIdx.x;
  int pt = blk % 144; int r = blk/144; int ch = r & 1; int b = r >> 1;
  int c0 = ch*64, pbase = pt*64;
  __shared__ float tile[64][65];
  int tr = threadIdx.x >> 2;
  int g  = threadIdx.x & 3;
  int c  = c0 + tr;
  float mu = st[(b*128+c)*2];
  float rs = st[(b*128+c)*2+1];
  const float* src = h2 + (size_t)(b*128+c)*HW + pbase + g*16;
  float* d = dsc + (size_t)(b*128+c)*HW + pbase + g*16;
  #pragma unroll
  for (int i=0;i<4;i++){
    float4 v = *(const float4*)(src + i*4);
    v.x=(v.x-mu)*rs; v.y=(v.y-mu)*rs; v.z=(v.z-mu)*rs; v.w=(v.w-mu)*rs;
    *(float4*)(d + i*4) = v;
    tile[tr][g*16+i*4+0]=v.x; tile[tr][g*16+i*4+1]=v.y;
    tile[tr][g*16+i*4+2]=v.z; tile[tr][g*16+i*4+3]=v.w;
  }
  __syncthreads();
  int pr = tr;
  u16* dt = dscT + ((size_t)b*HW + pbase + pr)*NC + c0 + g*16;
  u16* dl = dscL + ((size_t)b*HW + pbase + pr)*NC + c0 + g*16;
  #pragma unroll
  for (int i=0;i<4;i++){
    float v0 = tile[g*16+i*4+0][pr], v1 = tile[g*16+i*4+1][pr];
    float v2 = tile[g*16+i*4+2][pr], v3 = tile[g*16+i*4+3][pr];
    ushort4 hi = make_ushort4(f2b(v0), f2b(v1), f2b(v2), f2b(v3));
    ushort4 lo = make_ushort4(f2b(v0-bu2f(hi.x)), f2b(v1-bu2f(hi.y)),
                              f2b(v2-bu2f(hi.z)), f2b(v3-bu2f(hi.w)));
    *(ushort4*)(dt + i*4) = hi;
    *(ushort4*)(dl + i*4) = lo;
  }
}

// ---------------- K5: offset conv via MFMA, 32-px tiles (1152 blocks) ----------------
// Same proven 2-barrier pipeline, but M=32 per block: 2x blocks, same total gather work.
__global__ __launch_bounds__(256) void off_mfma(const u16* __restrict__ dscT,
    const u16* __restrict__ dscL, const u16* __restrict__ wob,
    const float* __restrict__ off_b, float4* __restrict__ wg, ushort4* __restrict__ ad){
  __shared__ short As[2][32*40];             // hi/lo A tiles (32 px x 32 K)
  __shared__ short Bs[32*40];                // W tile (32 o x 32 K)
  __shared__ float Po[18*32];                // offsets [o][px]
  int blk = blockIdx.x; int row0 = blk*32;   // 1152 blocks
  int b = rfl(row0/HW); int pbase = rfl(row0 - b*HW);
  int t = threadIdx.x;
  int apx = t>>3, hl = (t>>2)&1, segA = t&3; // A staging: px, hi/lo, 8-ch seg
  int bo = t>>3, bsegB = t&7;                // B staging: o row, 4-k seg
  int w = rfl(t>>6); int l = t&63; int q = l>>4; int ln = l&15;
  int mt = w&1, ntl = w>>1;                  // wave -> (m-tile, n-tile)
  int P = pbase + apx;
  int py = P/96, px_ = P - 96*(P/96);
  const u16* gsrc = (hl ? dscL : dscT) + (size_t)b*HW*NC;
  uint4 rg; ushort4 wb;
  auto prefetch = [&](int s){
    int k = s>>2, cseg = s&3;
    int y2 = py + k/3 - 1, x2 = px_ + k%3 - 1;
    bool valid = ((unsigned)y2 < 96u) && ((unsigned)x2 < 96u);
    int off = ((y2*96 + x2)*NC) + cseg*32 + segA*8;
    rg = valid ? *(const uint4*)(gsrc + off) : (uint4){0,0,0,0};
    wb = *(const ushort4*)(wob + bo*1152 + k*128 + cseg*32 + bsegB*4);
  };
  auto commit = [&](){
    *(short8*)&As[hl][apx*40 + segA*8] = *(short8*)&rg;
    *(ushort4*)&Bs[bo*40 + bsegB*4] = wb;
  };
  v4f acc = (v4f){0.f,0.f,0.f,0.f};
  prefetch(0); commit();
  __syncthreads();
  #pragma unroll 1
  for (int s=0;s<36;s++){
    if (s<35) prefetch(s+1);
    short8 ah = *(short8*)&As[0][(mt*16+ln)*40 + q*8];
    short8 al = *(short8*)&As[1][(mt*16+ln)*40 + q*8];
    short8 bf = *(short8*)&Bs[(ntl*16+ln)*40 + q*8];
    acc = __builtin_amdgcn_mfma_f32_16x16x32_bf16(ah, bf, acc, 0,0,0);
    acc = __builtin_amdgcn_mfma_f32_16x16x32_bf16(al, bf, acc, 0,0,0);
    __syncthreads();
    if (s<35){ commit(); __syncthreads(); }
  }
  int o = ntl*16 + ln;
  if (o < 18){
    float ob = off_b[o];
    #pragma unroll
    for (int r=0;r<4;r++) Po[o*32 + mt*16 + q*4 + r] = acc[r] + ob;
  }
  __syncthreads();
  #pragma unroll
  for (int i=0;i<2;i++){
    int idx = i*256 + t;
    if (idx < 288){
      int pxl = idx & 31, k = idx >> 5;
      int Pp = pbase + pxl;
      float dy = Po[(2*k)*32 + pxl], dx = Po[(2*k+1)*32 + pxl];
      float ys = (float)(Pp/96 + k/3 - 1) + dy;
      float xs = (float)(Pp%96 + k%3 - 1) + dx;
      float fy0 = floorf(ys), fx0 = floorf(xs);
      float wy = ys - fy0, wx = xs - fx0;
      int y0 = (int)fy0, x0 = (int)fx0;
      int y1 = y0+1, x1 = x0+1;
      float vy0 = (y0>=0 && y0<=95) ? 1.f : 0.f;
      float vy1 = (y1>=0 && y1<=95) ? 1.f : 0.f;
      float vx0 = (x0>=0 && x0<=95) ? 1.f : 0.f;
      float vx1 = (x1>=0 && x1<=95) ? 1.f : 0.f;
      int y0c=min(max(y0,0),95), y1c=min(max(y1,0),95);
      int x0c=min(max(x0,0),95), x1c=min(max(x1,0),95);
      float4 w4;
      w4.x = (1.f-wy)*(1.f-wx)*vy0*vx0;
      w4.y = (1.f-wy)*wx*vy0*vx1;
      w4.z = wy*(1.f-wx)*vy1*vx0;
      w4.w = wy*wx*vy1*vx1;
      int gi = (b*9 + k)*HW + pbase + pxl;
      wg[gi] = w4;
      ad[gi] = make_ushort4((u16)(y0c*WD+x0c), (u16)(y0c*WD+x1c),
                            (u16)(y1c*WD+x0c), (u16)(y1c*WD+x1c));
    }
  }
}

// ---------------- K6: deform conv, 32-px tiles, K-step 64 (1152 blocks, 18 steps) -------
// Same proven pipeline; no gather/combine duplication (each px gathered once).
// K-step 64 halves barrier count; wdcb stays L2-resident.
__global__ __launch_bounds__(256) void deform_mfma(const u16* __restrict__ dscT,
    const u16* __restrict__ wdcb, const float* __restrict__ dc_b,
    const float4* __restrict__ wg, const ushort4* __restrict__ ad,
    float* __restrict__ dc_t){
  __shared__ short As[32*72];                // 32 px x 64 K (pad 72)
  __shared__ short Bs[128*72];               // 128 o x 64 K
  int blk = blockIdx.x; int row0 = blk*32;   // 1152 blocks
  int b = rfl(row0/HW); int pbase = rfl(row0 - b*HW);
  int t = threadIdx.x;
  int apx = t>>3, cs8 = t&7;                 // A gather: px 0..31, 8-ch seg of 64
  int brow = t>>1, bs32 = (t&1)*32;          // B staging: o row, 32-short half of 64
  int w = rfl(t>>6); int l = t&63; int q = l>>4; int ln = l&15;
  int mt = w&1, nb = (w>>1)*4;               // wave -> (m-tile, n-tile base)
  const u16* db0 = dscT + (size_t)b*HW*NC;
  float4 wv; ushort4 av; uint4 r0,r1,r2,r3, wb0,wb1,wb2,wb3;
  auto prefetch = [&](int s){
    int k = s>>1; int cb = (s&1)<<6;         // tap, 64-ch half
    if (!(s&1)){ int wgi = (b*9 + k)*HW + pbase + apx; wv = wg[wgi]; av = ad[wgi]; }
    const u16* db = db0 + cb + cs8*8;
    r0 = *(const uint4*)(db + (int)av.x*NC);
    r1 = *(const uint4*)(db + (int)av.y*NC);
    r2 = *(const uint4*)(db + (int)av.z*NC);
    r3 = *(const uint4*)(db + (int)av.w*NC);
    const u16* wp = wdcb + brow*1152 + k*128 + cb + bs32;
    wb0 = *(const uint4*)(wp);
    wb1 = *(const uint4*)(wp + 8);
    wb2 = *(const uint4*)(wp + 16);
    wb3 = *(const uint4*)(wp + 24);
  };
  auto commit = [&](){
    const u16* pa=(const u16*)&r0; const u16* pb=(const u16*)&r1;
    const u16* pc=(const u16*)&r2; const u16* pd=(const u16*)&r3;
    short8 sv;
    #pragma unroll
    for (int j=0;j<8;j++){
      float f = wv.x*bu2f(pa[j]) + wv.y*bu2f(pb[j]) + wv.z*bu2f(pc[j]) + wv.w*bu2f(pd[j]);
      sv[j] = (short)f2b(f);
    }
    *(short8*)&As[apx*72 + cs8*8] = sv;
    *(short8*)&Bs[brow*72 + bs32 +  0] = *(short8*)&wb0;
    *(short8*)&Bs[brow*72 + bs32 +  8] = *(short8*)&wb1;
    *(short8*)&Bs[brow*72 + bs32 + 16] = *(short8*)&wb2;
    *(short8*)&Bs[brow*72 + bs32 + 24] = *(short8*)&wb3;
  };
  v4f acc[4];
  #pragma unroll
  for (int nt=0;nt<4;nt++) acc[nt] = (v4f){0.f,0.f,0.f,0.f};
  prefetch(0); commit();
  __syncthreads();
  #pragma unroll 1
  for (int s=0;s<18;s++){
    if (s<17) prefetch(s+1);
    #pragma unroll
    for (int ks=0;ks<2;ks++){
      short8 af = *(short8*)&As[(mt*16+ln)*72 + ks*32 + q*8];
      #pragma unroll
      for (int nt=0;nt<4;nt++){
        short8 bf = *(short8*)&Bs[((nb+nt)*16+ln)*72 + ks*32 + q*8];
        acc[nt] = __builtin_amdgcn_mfma_f32_16x16x32_bf16(af, bf, acc[nt], 0,0,0);
      }
    }
    __syncthreads();
    if (s<17){ commit(); __syncthreads(); }
  }
  #pragma unroll
  for (int nt=0;nt<4;nt++){
    int o = (nb+nt)*16 + ln;
    float bias = dc_b[o];
    #pragma unroll
    for (int r=0;r<4;r++){
      int px = pbase + mt*16 + q*4 + r;
      dc_t[((size_t)b*HW + px)*NC + o] = acc[nt][r] + bias;
    }
  }
}

// ---------------- K7: channel LayerNorm + sigmoid gate + multiply ----------------
__global__ __launch_bounds__(256) void epilogue(const float* __restrict__ dc_t,
    const float* __restrict__ dsc, const float* __restrict__ ln_g,
    const float* __restrict__ ln_b, float* __restrict__ out){
  __shared__ float T[64*129];
  __shared__ float Ps[4*64], Qs[4*64], Ms[64], Rs[64];
  int blk = blockIdx.x;
  int b = rfl(blk/144); int pbase = rfl(blk - (blk/144)*144)*64;
  int t = threadIdx.x;
  #pragma unroll
  for (int i=0;i<8;i++){
    int idx = i*256 + t; int px = idx>>5, seg = idx&31;
    float4 v = *(const float4*)(dc_t + ((size_t)b*HW + pbase + px)*NC + seg*4);
    float* d = &T[px*129 + seg*4];
    d[0]=v.x; d[1]=v.y; d[2]=v.z; d[3]=v.w;
  }
  __syncthreads();
  int px = t&63, cg = t>>6;
  float s=0.f, ss=0.f;
  #pragma unroll
  for (int i=0;i<32;i++){ float v = T[px*129 + cg*32 + i]; s += v; ss = fmaf(v,v,ss); }
  Ps[cg*64+px] = s; Qs[cg*64+px] = ss;
  __syncthreads();
  if (t<64){
    float S = Ps[px]+Ps[64+px]+Ps[128+px]+Ps[192+px];
    float SS= Qs[px]+Qs[64+px]+Qs[128+px]+Qs[192+px];
    float m = S*(1.f/128.f);
    float var = SS*(1.f/128.f) - m*m;
    Ms[px] = m; Rs[px] = rsqrtf(var + 1e-5f);
  }
  __syncthreads();
  float m = Ms[px], rs = Rs[px];
  #pragma unroll 4
  for (int i=0;i<32;i++){
    int c = cg*32 + i;
    float ln = (T[px*129+c] - m)*rs*ln_g[c] + ln_b[c];
    float attn = 1.f/(1.f+__expf(-ln));
    size_t idx = (size_t)(b*NC+c)*HW + pbase + px;
    out[idx] = dsc[idx]*attn;
  }
}

extern "C" void kernel_launch(void* const* d_in, const int* in_sizes, int n_in,
                              void* d_out, int out_size, void* d_ws, size_t ws_size,
                              hipStream_t stream){
  const float* x    = (const float*)d_in[0];
  const float* dw_w = (const float*)d_in[1];
  const float* dw_b = (const float*)d_in[2];
  const float* pw_w = (const float*)d_in[3];
  const float* pw_b = (const float*)d_in[4];
  const float* off_w= (const float*)d_in[5];
  const float* off_b= (const float*)d_in[6];
  const float* dc_w = (const float*)d_in[7];
  const float* dc_b = (const float*)d_in[8];
  const float* ln_g = (const float*)d_in[9];
  const float* ln_b = (const float*)d_in[10];
  float* out = (float*)d_out;

  float* W    = (float*)d_ws;
  float*   bufA = W;                          // h1, then dsc (NCHW f32)
  float*   bufB = W + 4718592;                // h2, then dc_t (NHWC f32)
  u16*     dscT = (u16*)(W + 9437184);        // NHWC bf16 hi (4718592 u16)
  u16*     dscL = (u16*)(W + 11796480);       // NHWC bf16 lo residual
  float4*  wg   = (float4*)(W + 14155776);    // 331776 float4
  ushort4* ad   = (ushort4*)(W + 15482880);   // 331776 ushort4
  float*   st   = W + 16146432;
  u16*     wpwb = (u16*)(W + 16147456);       // 16384 u16
  u16*     wob  = (u16*)(W + 16155648);       // 36864 u16
  u16*     wdcb = (u16*)(W + 16174080);       // 147456 u16

  prep_weights<<<576, 256, 0, stream>>>(pw_w, off_w, dc_w, wpwb, wob, wdcb);
  dw_conv     <<<18432, 256, 0, stream>>>(x, dw_w, dw_b, bufA);
  pw_mfma     <<<576, 256, 0, stream>>>(bufA, wpwb, pw_b, bufB);
  inorm_stats <<<512, 256, 0, stream>>>(bufB, st);
  make_dsc    <<<1152, 256, 0, stream>>>(bufB, st, bufA, dscT, dscL);
  off_mfma    <<<1152, 256, 0, stream>>>(dscT, dscL, wob, off_b, wg, ad);
  deform_mfma <<<1152, 256, 0, stream>>>(dscT, wdcb, dc_b, wg, ad, bufB);
  epilogue    <<<576, 256, 0, stream>>>(bufB, bufA, ln_g, ln_b, out);
}

// Round 6
// 236.617 us; speedup vs baseline: 1.1619x; 1.0230x over previous
//
#include <hip/hip_runtime.h>
#include <math.h>

#define HW 9216
#define WD 96
#define NC 128

typedef unsigned short u16;
typedef __attribute__((ext_vector_type(8))) short short8;
typedef __attribute__((ext_vector_type(4))) float v4f;

__device__ __forceinline__ int rfl(int v){ return __builtin_amdgcn_readfirstlane(v); }
__device__ __forceinline__ float bu2f(u16 s){ return __uint_as_float(((unsigned)s)<<16); }
__device__ __forceinline__ u16 f2b(float f){ unsigned u = __float_as_uint(f);
  return (u16)((u + 0x7fffu + ((u>>16)&1u))>>16); }

// ---------------- K0: weight prep ----------------
__global__ __launch_bounds__(256) void prep_weights(const float* __restrict__ pw_w,
    const float* __restrict__ off_w, const float* __restrict__ dc_w,
    u16* __restrict__ wpwb, u16* __restrict__ wob, u16* __restrict__ wdcb){
  int t = blockIdx.x*256 + threadIdx.x;
  if (t < 16384) wpwb[t] = f2b(pw_w[t]);
  if (t < 36864){ int o = t/1152, r = t - o*1152; int k = r>>7, c = r&127;
                  wob[t] = (o<18) ? f2b(off_w[(o*128+c)*9+k]) : (u16)0; }
  if (t < 147456){ int o = t/1152, r = t - o*1152; int k = r>>7, c = r&127;
                   wdcb[t] = f2b(dc_w[(o*128+c)*9 + k]); }
}

// ---------------- K1: depthwise 3x3 + bias (NCHW fp32) ----------------
__global__ __launch_bounds__(256) void dw_conv(const float* __restrict__ x,
    const float* __restrict__ w, const float* __restrict__ bias, float* __restrict__ h1){
  int n = blockIdx.x*256 + threadIdx.x;
  int bc = rfl(n / HW);
  int p = n - bc*HW;
  int c = bc & 127;
  int yy = p / WD, xx = p - (p/WD)*WD;
  const float* xc = x + (size_t)bc*HW;
  float acc = bias[c];
  #pragma unroll
  for (int r=0;r<3;r++){
    int y2 = yy + r - 1;
    #pragma unroll
    for (int cc2=0;cc2<3;cc2++){
      int x2 = xx + cc2 - 1;
      if (y2>=0 && y2<96 && x2>=0 && x2<96)
        acc = fmaf(w[c*9 + r*3 + cc2], xc[y2*WD + x2], acc);
    }
  }
  h1[n] = acc;
}

// ---------------- K2: pointwise 1x1 via MFMA ----------------
__global__ __launch_bounds__(256) void pw_mfma(const float* __restrict__ h1,
    const u16* __restrict__ wpwb, const float* __restrict__ pw_b, float* __restrict__ h2){
  __shared__ short Aw[128*136];
  __shared__ short Bw[128*68];
  int blk = blockIdx.x; int row0 = blk*64;
  int b = rfl(row0/HW); int pbase = rfl(row0 - b*HW);
  int t = threadIdx.x;
  #pragma unroll
  for (int i=0;i<8;i++){
    int idx = i*256 + t; int o = idx>>4, seg = idx&15;
    *(short8*)&Aw[o*136 + seg*8] = *(const short8*)(wpwb + o*128 + seg*8);
  }
  #pragma unroll
  for (int i=0;i<8;i++){
    int idx = i*256 + t; int c = idx>>4, seg = idx&15;
    float4 v = *(const float4*)(h1 + (size_t)(b*NC+c)*HW + pbase + seg*4);
    ushort4 pk = make_ushort4(f2b(v.x), f2b(v.y), f2b(v.z), f2b(v.w));
    *(ushort4*)&Bw[c*68 + seg*4] = pk;
  }
  __syncthreads();
  int w = rfl(t>>6); int l = t&63; int q = l>>4; int ln = l&15;
  v4f acc[8];
  #pragma unroll
  for (int mt=0;mt<8;mt++) acc[mt] = (v4f){0.f,0.f,0.f,0.f};
  #pragma unroll
  for (int ks=0;ks<4;ks++){
    short8 bf;
    #pragma unroll
    for (int j=0;j<8;j++) bf[j] = Bw[(ks*32 + q*8 + j)*68 + w*16 + ln];
    #pragma unroll
    for (int mt=0;mt<8;mt++){
      short8 af = *(short8*)&Aw[(mt*16+ln)*136 + ks*32 + q*8];
      acc[mt] = __builtin_amdgcn_mfma_f32_16x16x32_bf16(af, bf, acc[mt], 0,0,0);
    }
  }
  int px = pbase + w*16 + ln;
  #pragma unroll
  for (int mt=0;mt<8;mt++){
    #pragma unroll
    for (int r=0;r<4;r++){
      int o = mt*16 + q*4 + r;
      h2[(size_t)(b*NC+o)*HW + px] = acc[mt][r] + pw_b[o];
    }
  }
}

// ---------------- K3: InstanceNorm stats ----------------
__global__ __launch_bounds__(256) void inorm_stats(const float* __restrict__ h2, float* __restrict__ st){
  int bc = blockIdx.x;
  const float* src = h2 + (size_t)bc*HW;
  float s=0.f, ss=0.f;
  for (int i=threadIdx.x; i<HW; i+=256){ float v=src[i]; s+=v; ss=fmaf(v,v,ss); }
  #pragma unroll
  for (int off=32; off; off>>=1){ s += __shfl_down(s,off); ss += __shfl_down(ss,off); }
  __shared__ float rsm[2][4];
  int wave = threadIdx.x>>6, lane = threadIdx.x&63;
  if (lane==0){ rsm[0][wave]=s; rsm[1][wave]=ss; }
  __syncthreads();
  if (threadIdx.x==0){
    float S = rsm[0][0]+rsm[0][1]+rsm[0][2]+rsm[0][3];
    float SS= rsm[1][0]+rsm[1][1]+rsm[1][2]+rsm[1][3];
    float mu = S * (1.f/9216.f);
    float var = SS * (1.f/9216.f) - mu*mu;
    st[bc*2]   = mu;
    st[bc*2+1] = rsqrtf(var + 1e-5f);
  }
}

// ---------------- K4: dsc (NCHW fp32) + dscT/dscL (NHWC bf16 hi/lo) ----------------
__global__ __launch_bounds__(256) void make_dsc(const float* __restrict__ h2,
    const float* __restrict__ st, float* __restrict__ dsc,
    u16* __restrict__ dscT, u16* __restrict__ dscL){
  int blk = blockIdx.x;
  int pt = blk % 144; int r = blk/144; int ch = r & 1; int b = r >> 1;
  int c0 = ch*64, pbase = pt*64;
  __shared__ float tile[64][65];
  int tr = threadIdx.x >> 2;
  int g  = threadIdx.x & 3;
  int c  = c0 + tr;
  float mu = st[(b*128+c)*2];
  float rs = st[(b*128+c)*2+1];
  const float* src = h2 + (size_t)(b*128+c)*HW + pbase + g*16;
  float* d = dsc + (size_t)(b*128+c)*HW + pbase + g*16;
  #pragma unroll
  for (int i=0;i<4;i++){
    float4 v = *(const float4*)(src + i*4);
    v.x=(v.x-mu)*rs; v.y=(v.y-mu)*rs; v.z=(v.z-mu)*rs; v.w=(v.w-mu)*rs;
    *(float4*)(d + i*4) = v;
    tile[tr][g*16+i*4+0]=v.x; tile[tr][g*16+i*4+1]=v.y;
    tile[tr][g*16+i*4+2]=v.z; tile[tr][g*16+i*4+3]=v.w;
  }
  __syncthreads();
  int pr = tr;
  u16* dt = dscT + ((size_t)b*HW + pbase + pr)*NC + c0 + g*16;
  u16* dl = dscL + ((size_t)b*HW + pbase + pr)*NC + c0 + g*16;
  #pragma unroll
  for (int i=0;i<4;i++){
    float v0 = tile[g*16+i*4+0][pr], v1 = tile[g*16+i*4+1][pr];
    float v2 = tile[g*16+i*4+2][pr], v3 = tile[g*16+i*4+3][pr];
    ushort4 hi = make_ushort4(f2b(v0), f2b(v1), f2b(v2), f2b(v3));
    ushort4 lo = make_ushort4(f2b(v0-bu2f(hi.x)), f2b(v1-bu2f(hi.y)),
                              f2b(v2-bu2f(hi.z)), f2b(v3-bu2f(hi.w)));
    *(ushort4*)(dt + i*4) = hi;
    *(ushort4*)(dl + i*4) = lo;
  }
}

// ---------------- K5: offset conv via MFMA, 32-px tiles, XCD-swizzled ----------------
// tile = (blk%8)*144 + blk/8: with round-robin blockIdx%8 -> XCD, each XCD owns 144
// contiguous tiles (48 rows of one batch). Gather working set (dscT+dscL slab ~2.5MB
// + wob) fits the 4MiB per-XCD L2 -> tap re-reads become L2 hits, not HBM fetches.
__global__ __launch_bounds__(256) void off_mfma(const u16* __restrict__ dscT,
    const u16* __restrict__ dscL, const u16* __restrict__ wob,
    const float* __restrict__ off_b, float4* __restrict__ wg, ushort4* __restrict__ ad){
  __shared__ short As[2][32*40];             // hi/lo A tiles (32 px x 32 K)
  __shared__ short Bs[32*40];                // W tile (32 o x 32 K)
  __shared__ float Po[18*32];                // offsets [o][px]
  int blk = blockIdx.x;                      // 1152 blocks = 8 * 144
  int tile = (blk&7)*144 + (blk>>3);
  int row0 = tile*32;
  int b = rfl(row0/HW); int pbase = rfl(row0 - b*HW);
  int t = threadIdx.x;
  int apx = t>>3, hl = (t>>2)&1, segA = t&3; // A staging: px, hi/lo, 8-ch seg
  int bo = t>>3, bsegB = t&7;                // B staging: o row, 4-k seg
  int w = rfl(t>>6); int l = t&63; int q = l>>4; int ln = l&15;
  int mt = w&1, ntl = w>>1;                  // wave -> (m-tile, n-tile)
  int P = pbase + apx;
  int py = P/96, px_ = P - 96*(P/96);
  const u16* gsrc = (hl ? dscL : dscT) + (size_t)b*HW*NC;
  uint4 rg; ushort4 wb;
  auto prefetch = [&](int s){
    int k = s>>2, cseg = s&3;
    int y2 = py + k/3 - 1, x2 = px_ + k%3 - 1;
    bool valid = ((unsigned)y2 < 96u) && ((unsigned)x2 < 96u);
    int off = ((y2*96 + x2)*NC) + cseg*32 + segA*8;
    rg = valid ? *(const uint4*)(gsrc + off) : (uint4){0,0,0,0};
    wb = *(const ushort4*)(wob + bo*1152 + k*128 + cseg*32 + bsegB*4);
  };
  auto commit = [&](){
    *(short8*)&As[hl][apx*40 + segA*8] = *(short8*)&rg;
    *(ushort4*)&Bs[bo*40 + bsegB*4] = wb;
  };
  v4f acc = (v4f){0.f,0.f,0.f,0.f};
  prefetch(0); commit();
  __syncthreads();
  #pragma unroll 1
  for (int s=0;s<36;s++){
    if (s<35) prefetch(s+1);
    short8 ah = *(short8*)&As[0][(mt*16+ln)*40 + q*8];
    short8 al = *(short8*)&As[1][(mt*16+ln)*40 + q*8];
    short8 bf = *(short8*)&Bs[(ntl*16+ln)*40 + q*8];
    acc = __builtin_amdgcn_mfma_f32_16x16x32_bf16(ah, bf, acc, 0,0,0);
    acc = __builtin_amdgcn_mfma_f32_16x16x32_bf16(al, bf, acc, 0,0,0);
    __syncthreads();
    if (s<35){ commit(); __syncthreads(); }
  }
  int o = ntl*16 + ln;
  if (o < 18){
    float ob = off_b[o];
    #pragma unroll
    for (int r=0;r<4;r++) Po[o*32 + mt*16 + q*4 + r] = acc[r] + ob;
  }
  __syncthreads();
  #pragma unroll
  for (int i=0;i<2;i++){
    int idx = i*256 + t;
    if (idx < 288){
      int pxl = idx & 31, k = idx >> 5;
      int Pp = pbase + pxl;
      float dy = Po[(2*k)*32 + pxl], dx = Po[(2*k+1)*32 + pxl];
      float ys = (float)(Pp/96 + k/3 - 1) + dy;
      float xs = (float)(Pp%96 + k%3 - 1) + dx;
      float fy0 = floorf(ys), fx0 = floorf(xs);
      float wy = ys - fy0, wx = xs - fx0;
      int y0 = (int)fy0, x0 = (int)fx0;
      int y1 = y0+1, x1 = x0+1;
      float vy0 = (y0>=0 && y0<=95) ? 1.f : 0.f;
      float vy1 = (y1>=0 && y1<=95) ? 1.f : 0.f;
      float vx0 = (x0>=0 && x0<=95) ? 1.f : 0.f;
      float vx1 = (x1>=0 && x1<=95) ? 1.f : 0.f;
      int y0c=min(max(y0,0),95), y1c=min(max(y1,0),95);
      int x0c=min(max(x0,0),95), x1c=min(max(x1,0),95);
      float4 w4;
      w4.x = (1.f-wy)*(1.f-wx)*vy0*vx0;
      w4.y = (1.f-wy)*wx*vy0*vx1;
      w4.z = wy*(1.f-wx)*vy1*vx0;
      w4.w = wy*wx*vy1*vx1;
      int gi = (b*9 + k)*HW + pbase + pxl;
      wg[gi] = w4;
      ad[gi] = make_ushort4((u16)(y0c*WD+x0c), (u16)(y0c*WD+x1c),
                            (u16)(y1c*WD+x0c), (u16)(y1c*WD+x1c));
    }
  }
}

// ---------------- K6: deform conv, 32-px tiles, K-step 64, XCD-swizzled --------------
// Same swizzle as K5: each XCD owns a contiguous 48-row slab; dscT slab (~1.2MB) +
// wdcb (288KB) + wg/ad slab (~1MB) fit per-XCD L2 -> gather re-reads are L2 hits.
__global__ __launch_bounds__(256) void deform_mfma(const u16* __restrict__ dscT,
    const u16* __restrict__ wdcb, const float* __restrict__ dc_b,
    const float4* __restrict__ wg, const ushort4* __restrict__ ad,
    float* __restrict__ dc_t){
  __shared__ short As[32*72];                // 32 px x 64 K (pad 72)
  __shared__ short Bs[128*72];               // 128 o x 64 K
  int blk = blockIdx.x;                      // 1152 blocks = 8 * 144
  int tile = (blk&7)*144 + (blk>>3);
  int row0 = tile*32;
  int b = rfl(row0/HW); int pbase = rfl(row0 - b*HW);
  int t = threadIdx.x;
  int apx = t>>3, cs8 = t&7;                 // A gather: px 0..31, 8-ch seg of 64
  int brow = t>>1, bs32 = (t&1)*32;          // B staging: o row, 32-short half of 64
  int w = rfl(t>>6); int l = t&63; int q = l>>4; int ln = l&15;
  int mt = w&1, nb = (w>>1)*4;               // wave -> (m-tile, n-tile base)
  const u16* db0 = dscT + (size_t)b*HW*NC;
  float4 wv; ushort4 av; uint4 r0,r1,r2,r3, wb0,wb1,wb2,wb3;
  auto prefetch = [&](int s){
    int k = s>>1; int cb = (s&1)<<6;         // tap, 64-ch half
    if (!(s&1)){ int wgi = (b*9 + k)*HW + pbase + apx; wv = wg[wgi]; av = ad[wgi]; }
    const u16* db = db0 + cb + cs8*8;
    r0 = *(const uint4*)(db + (int)av.x*NC);
    r1 = *(const uint4*)(db + (int)av.y*NC);
    r2 = *(const uint4*)(db + (int)av.z*NC);
    r3 = *(const uint4*)(db + (int)av.w*NC);
    const u16* wp = wdcb + brow*1152 + k*128 + cb + bs32;
    wb0 = *(const uint4*)(wp);
    wb1 = *(const uint4*)(wp + 8);
    wb2 = *(const uint4*)(wp + 16);
    wb3 = *(const uint4*)(wp + 24);
  };
  auto commit = [&](){
    const u16* pa=(const u16*)&r0; const u16* pb=(const u16*)&r1;
    const u16* pc=(const u16*)&r2; const u16* pd=(const u16*)&r3;
    short8 sv;
    #pragma unroll
    for (int j=0;j<8;j++){
      float f = wv.x*bu2f(pa[j]) + wv.y*bu2f(pb[j]) + wv.z*bu2f(pc[j]) + wv.w*bu2f(pd[j]);
      sv[j] = (short)f2b(f);
    }
    *(short8*)&As[apx*72 + cs8*8] = sv;
    *(short8*)&Bs[brow*72 + bs32 +  0] = *(short8*)&wb0;
    *(short8*)&Bs[brow*72 + bs32 +  8] = *(short8*)&wb1;
    *(short8*)&Bs[brow*72 + bs32 + 16] = *(short8*)&wb2;
    *(short8*)&Bs[brow*72 + bs32 + 24] = *(short8*)&wb3;
  };
  v4f acc[4];
  #pragma unroll
  for (int nt=0;nt<4;nt++) acc[nt] = (v4f){0.f,0.f,0.f,0.f};
  prefetch(0); commit();
  __syncthreads();
  #pragma unroll 1
  for (int s=0;s<18;s++){
    if (s<17) prefetch(s+1);
    #pragma unroll
    for (int ks=0;ks<2;ks++){
      short8 af = *(short8*)&As[(mt*16+ln)*72 + ks*32 + q*8];
      #pragma unroll
      for (int nt=0;nt<4;nt++){
        short8 bf = *(short8*)&Bs[((nb+nt)*16+ln)*72 + ks*32 + q*8];
        acc[nt] = __builtin_amdgcn_mfma_f32_16x16x32_bf16(af, bf, acc[nt], 0,0,0);
      }
    }
    __syncthreads();
    if (s<17){ commit(); __syncthreads(); }
  }
  #pragma unroll
  for (int nt=0;nt<4;nt++){
    int o = (nb+nt)*16 + ln;
    float bias = dc_b[o];
    #pragma unroll
    for (int r=0;r<4;r++){
      int px = pbase + mt*16 + q*4 + r;
      dc_t[((size_t)b*HW + px)*NC + o] = acc[nt][r] + bias;
    }
  }
}

// ---------------- K7: channel LayerNorm + sigmoid gate + multiply ----------------
__global__ __launch_bounds__(256) void epilogue(const float* __restrict__ dc_t,
    const float* __restrict__ dsc, const float* __restrict__ ln_g,
    const float* __restrict__ ln_b, float* __restrict__ out){
  __shared__ float T[64*129];
  __shared__ float Ps[4*64], Qs[4*64], Ms[64], Rs[64];
  int blk = blockIdx.x;
  int b = rfl(blk/144); int pbase = rfl(blk - (blk/144)*144)*64;
  int t = threadIdx.x;
  #pragma unroll
  for (int i=0;i<8;i++){
    int idx = i*256 + t; int px = idx>>5, seg = idx&31;
    float4 v = *(const float4*)(dc_t + ((size_t)b*HW + pbase + px)*NC + seg*4);
    float* d = &T[px*129 + seg*4];
    d[0]=v.x; d[1]=v.y; d[2]=v.z; d[3]=v.w;
  }
  __syncthreads();
  int px = t&63, cg = t>>6;
  float s=0.f, ss=0.f;
  #pragma unroll
  for (int i=0;i<32;i++){ float v = T[px*129 + cg*32 + i]; s += v; ss = fmaf(v,v,ss); }
  Ps[cg*64+px] = s; Qs[cg*64+px] = ss;
  __syncthreads();
  if (t<64){
    float S = Ps[px]+Ps[64+px]+Ps[128+px]+Ps[192+px];
    float SS= Qs[px]+Qs[64+px]+Qs[128+px]+Qs[192+px];
    float m = S*(1.f/128.f);
    float var = SS*(1.f/128.f) - m*m;
    Ms[px] = m; Rs[px] = rsqrtf(var + 1e-5f);
  }
  __syncthreads();
  float m = Ms[px], rs = Rs[px];
  #pragma unroll 4
  for (int i=0;i<32;i++){
    int c = cg*32 + i;
    float ln = (T[px*129+c] - m)*rs*ln_g[c] + ln_b[c];
    float attn = 1.f/(1.f+__expf(-ln));
    size_t idx = (size_t)(b*NC+c)*HW + pbase + px;
    out[idx] = dsc[idx]*attn;
  }
}

extern "C" void kernel_launch(void* const* d_in, const int* in_sizes, int n_in,
                              void* d_out, int out_size, void* d_ws, size_t ws_size,
                              hipStream_t stream){
  const float* x    = (const float*)d_in[0];
  const float* dw_w = (const float*)d_in[1];
  const float* dw_b = (const float*)d_in[2];
  const float* pw_w = (const float*)d_in[3];
  const float* pw_b = (const float*)d_in[4];
  const float* off_w= (const float*)d_in[5];
  const float* off_b= (const float*)d_in[6];
  const float* dc_w = (const float*)d_in[7];
  const float* dc_b = (const float*)d_in[8];
  const float* ln_g = (const float*)d_in[9];
  const float* ln_b = (const float*)d_in[10];
  float* out = (float*)d_out;

  float* W    = (float*)d_ws;
  float*   bufA = W;                          // h1, then dsc (NCHW f32)
  float*   bufB = W + 4718592;                // h2, then dc_t (NHWC f32)
  u16*     dscT = (u16*)(W + 9437184);        // NHWC bf16 hi (4718592 u16)
  u16*     dscL = (u16*)(W + 11796480);       // NHWC bf16 lo residual
  float4*  wg   = (float4*)(W + 14155776);    // 331776 float4
  ushort4* ad   = (ushort4*)(W + 15482880);   // 331776 ushort4
  float*   st   = W + 16146432;
  u16*     wpwb = (u16*)(W + 16147456);       // 16384 u16
  u16*     wob  = (u16*)(W + 16155648);       // 36864 u16
  u16*     wdcb = (u16*)(W + 16174080);       // 147456 u16

  prep_weights<<<576, 256, 0, stream>>>(pw_w, off_w, dc_w, wpwb, wob, wdcb);
  dw_conv     <<<18432, 256, 0, stream>>>(x, dw_w, dw_b, bufA);
  pw_mfma     <<<576, 256, 0, stream>>>(bufA, wpwb, pw_b, bufB);
  inorm_stats <<<512, 256, 0, stream>>>(bufB, st);
  make_dsc    <<<1152, 256, 0, stream>>>(bufB, st, bufA, dscT, dscL);
  off_mfma    <<<1152, 256, 0, stream>>>(dscT, dscL, wob, off_b, wg, ad);
  deform_mfma <<<1152, 256, 0, stream>>>(dscT, wdcb, dc_b, wg, ad, bufB);
  epilogue    <<<576, 256, 0, stream>>>(bufB, bufA, ln_g, ln_b, out);
}